// Round 1
// baseline (3928.259 us; speedup 1.0000x reference)
//
#include <hip/hip_runtime.h>
#include <hip/hip_bf16.h>

// Problem constants (match reference)
constexpr int V  = 100000;
constexpr int E  = 1600000;
constexpr int LN = 64;
constexpr int S  = 8;
constexpr int NET = 10;
constexpr int KX = 2 * LN + NET;   // 138
constexpr int WROW = 140;          // W_xi LDS row stride (floats), 16B-aligned
constexpr int WRROW = 68;          // W_rou LDS row stride (floats)
constexpr int XROW = 132;          // X LDS row stride (floats), 16B-aligned
constexpr float MUS = 0.1125f;     // MU / S

__device__ __forceinline__ float fast_tanh(float x) {
    // tanh(x) = 1 - 2/(exp(2x)+1); saturates correctly for large |x|
    return 1.0f - 2.0f / (__expf(2.0f * x) + 1.0f);
}

__device__ __forceinline__ float bflo(unsigned u) { return __uint_as_float(u << 16); }
__device__ __forceinline__ float bfhi(unsigned u) { return __uint_as_float(u & 0xffff0000u); }

// ---------------------------------------------------------------------------
// Kernel 1: per-edge A (bf16, E x 64) and bias (fp32, E x 8)
// grid: 1000 blocks x 256 threads = 4000 waves; each wave does 50 batches of 8 edges
// ---------------------------------------------------------------------------
__global__ __launch_bounds__(256) void precompute_kernel(
    const float* __restrict__ feat, const int* __restrict__ xnode,
    const int* __restrict__ xneis, const int* __restrict__ etype,
    const float* __restrict__ dg, const float* __restrict__ Wxi,
    const float* __restrict__ bxi, const float* __restrict__ Wrou,
    const float* __restrict__ brou,
    __hip_bfloat16* __restrict__ Aout, float* __restrict__ biasOut)
{
    __shared__ float Wlds[64 * WROW];       // 35840 B
    __shared__ float Wrlds[8 * WRROW];      // 2176 B
    __shared__ float Xlds[4][8][XROW];      // 16896 B

    const int tid = threadIdx.x;

    // stage W_xi (64 x 138, zero-pad to 140)
    for (int i = tid; i < 64 * WROW; i += 256) {
        int r = i / WROW, c = i - r * WROW;
        Wlds[i] = (c < KX) ? Wxi[r * KX + c] : 0.0f;
    }
    // stage W_rou (8 x 64, pad row to 68; pad entries never read)
    for (int i = tid; i < 8 * 64; i += 256) {
        int r = i >> 6, c = i & 63;
        Wrlds[r * WRROW + c] = Wrou[i];
    }
    __syncthreads();

    const int wave = tid >> 6;
    const int lane = tid & 63;
    const int gw = blockIdx.x * 4 + wave;       // 0..3999
    const float bx = bxi[lane];

    for (int it = 0; it < 50; ++it) {
        const int batch = it * 4000 + gw;       // 0..199999
        const int e0 = batch * 8;

        // per-edge metadata in lanes 0..7
        int src = 0, nei = 0, et = 0; float dgv = 1.0f;
        if (lane < 8) {
            src = xnode[e0 + lane] - 1;
            nei = xneis[e0 + lane] - 1;
            et  = etype[e0 + lane] - 1;
            dgv = dg[e0 + lane];
        }

        // stage X rows: [node_emb(64) | neis_emb(64)]
        #pragma unroll
        for (int j = 0; j < 8; ++j) {
            int s_j = __shfl(src, j);
            int n_j = __shfl(nei, j);
            Xlds[wave][j][lane]      = feat[(size_t)s_j * 64 + lane];
            Xlds[wave][j][64 + lane] = feat[(size_t)n_j * 64 + lane];
        }
        __syncthreads();

        // lane t computes A[e_j][t] for j=0..7
        float acc[8];
        #pragma unroll
        for (int j = 0; j < 8; ++j) acc[j] = bx;

        const float4* W4 = (const float4*)(&Wlds[lane * WROW]);
        #pragma unroll 4
        for (int k = 0; k < 32; ++k) {
            float4 w = W4[k];
            #pragma unroll
            for (int j = 0; j < 8; ++j) {
                float4 x = ((const float4*)(&Xlds[wave][j][0]))[k];
                acc[j] += w.x * x.x + w.y * x.y + w.z * x.z + w.w * x.w;
            }
        }
        #pragma unroll
        for (int j = 0; j < 8; ++j) {
            int   et_j = __shfl(et, j);
            float dg_j = __shfl(dgv, j);
            float a = acc[j] + Wlds[lane * WROW + 128 + et_j];
            float val = fast_tanh(a) * (MUS / dg_j);
            Aout[(size_t)(e0 + j) * 64 + lane] = __float2bfloat16(val);
        }

        // bias: lane -> edge j = lane/8, output tp = lane%8
        {
            int j = lane >> 3, tp = lane & 7;
            float accb = brou[tp];
            const float4* Xn4 = (const float4*)(&Xlds[wave][j][0]);
            const float4* Wr4 = (const float4*)(&Wrlds[tp * WRROW]);
            #pragma unroll
            for (int k = 0; k < 16; ++k) {
                float4 x = Xn4[16 + k];   // neis_emb part
                float4 w = Wr4[k];
                accb += x.x * w.x + x.y * w.y + x.z * w.z + x.w * w.w;
            }
            biasOut[(size_t)(e0 + j) * 8 + tp] = fast_tanh(accb);
        }
        __syncthreads();
    }
}

// ---------------------------------------------------------------------------
// Kernel 2: one recurrence step. out_e = A_e * H[src_e] + bias_e, scatter-add
// by RAW 1-indexed X_Neis (drop id == V; segment 0 stays zero).
// ---------------------------------------------------------------------------
__global__ __launch_bounds__(256) void step_kernel(
    const float* __restrict__ Hin, float* __restrict__ Hout,
    const __hip_bfloat16* __restrict__ A, const float* __restrict__ bias,
    const int* __restrict__ xnode, const int* __restrict__ xneis)
{
    int e = blockIdx.x * 256 + threadIdx.x;
    if (e >= E) return;

    int src = xnode[e] - 1;
    int nr  = xneis[e];                       // raw 1-indexed scatter target

    const float4* H4 = (const float4*)(Hin + (size_t)src * 8);
    float4 h0 = H4[0], h1 = H4[1];
    float he[8] = {h0.x, h0.y, h0.z, h0.w, h1.x, h1.y, h1.z, h1.w};

    const float4* B4 = (const float4*)(bias + (size_t)e * 8);
    float4 b0 = B4[0], b1 = B4[1];
    float out[8] = {b0.x, b0.y, b0.z, b0.w, b1.x, b1.y, b1.z, b1.w};

    const uint4* A4 = (const uint4*)(A + (size_t)e * 64);
    #pragma unroll
    for (int r = 0; r < 8; ++r) {
        uint4 av = A4[r];
        out[r] += bflo(av.x) * he[0] + bfhi(av.x) * he[1]
                + bflo(av.y) * he[2] + bfhi(av.y) * he[3]
                + bflo(av.z) * he[4] + bfhi(av.z) * he[5]
                + bflo(av.w) * he[6] + bfhi(av.w) * he[7];
    }

    if (nr < V) {
        float* dst = Hout + (size_t)nr * 8;
        #pragma unroll
        for (int i = 0; i < 8; ++i) atomicAdd(dst + i, out[i]);
    }
}

// ---------------------------------------------------------------------------
// Epilogue kernels
// ---------------------------------------------------------------------------
__global__ __launch_bounds__(256) void logits_kernel(
    const float* __restrict__ H, const float* __restrict__ W1,
    const float* __restrict__ b1, float* __restrict__ logits)
{
    int v = blockIdx.x * 256 + threadIdx.x;
    if (v >= V) return;
    float4 w0 = ((const float4*)W1)[0], w1 = ((const float4*)W1)[1];
    const float4* H4 = (const float4*)(H + (size_t)v * 8);
    float4 h0 = H4[0], h1 = H4[1];
    float l = b1[0]
            + h0.x * w0.x + h0.y * w0.y + h0.z * w0.z + h0.w * w0.w
            + h1.x * w1.x + h1.y * w1.y + h1.z * w1.z + h1.w * w1.w;
    logits[v] = l;
}

__global__ __launch_bounds__(256) void reduce_max_kernel(
    const float* __restrict__ logits, float* __restrict__ partial)
{
    float m = -INFINITY;
    for (int v = blockIdx.x * 256 + threadIdx.x; v < V; v += 256 * 256)
        m = fmaxf(m, logits[v]);
    #pragma unroll
    for (int o = 32; o > 0; o >>= 1) m = fmaxf(m, __shfl_down(m, o));
    __shared__ float sm[4];
    if ((threadIdx.x & 63) == 0) sm[threadIdx.x >> 6] = m;
    __syncthreads();
    if (threadIdx.x == 0)
        partial[blockIdx.x] = fmaxf(fmaxf(sm[0], sm[1]), fmaxf(sm[2], sm[3]));
}

__global__ __launch_bounds__(256) void final_max_kernel(
    const float* __restrict__ partial, float* __restrict__ M)
{
    float m = partial[threadIdx.x];
    #pragma unroll
    for (int o = 32; o > 0; o >>= 1) m = fmaxf(m, __shfl_down(m, o));
    __shared__ float sm[4];
    if ((threadIdx.x & 63) == 0) sm[threadIdx.x >> 6] = m;
    __syncthreads();
    if (threadIdx.x == 0) *M = fmaxf(fmaxf(sm[0], sm[1]), fmaxf(sm[2], sm[3]));
}

__global__ __launch_bounds__(256) void sum_kernel(
    const float* __restrict__ H, const float* __restrict__ logits,
    const float* __restrict__ Mp, float* __restrict__ accum)
{
    const float M = *Mp;
    float se = 0.0f;
    float sh[8] = {0, 0, 0, 0, 0, 0, 0, 0};
    for (int v = blockIdx.x * 256 + threadIdx.x; v < V; v += 256 * 256) {
        float w = __expf(logits[v] - M);
        se += w;
        const float4* H4 = (const float4*)(H + (size_t)v * 8);
        float4 h0 = H4[0], h1 = H4[1];
        sh[0] += w * h0.x; sh[1] += w * h0.y; sh[2] += w * h0.z; sh[3] += w * h0.w;
        sh[4] += w * h1.x; sh[5] += w * h1.y; sh[6] += w * h1.z; sh[7] += w * h1.w;
    }
    #pragma unroll
    for (int o = 32; o > 0; o >>= 1) {
        se += __shfl_down(se, o);
        #pragma unroll
        for (int i = 0; i < 8; ++i) sh[i] += __shfl_down(sh[i], o);
    }
    if ((threadIdx.x & 63) == 0) {
        atomicAdd(&accum[8], se);
        #pragma unroll
        for (int i = 0; i < 8; ++i) atomicAdd(&accum[i], sh[i]);
    }
}

__global__ void final_kernel(const float* __restrict__ accum, float* __restrict__ out)
{
    if (threadIdx.x < 8) out[threadIdx.x] = tanhf(accum[threadIdx.x] / accum[8]);
}

// ---------------------------------------------------------------------------
extern "C" void kernel_launch(void* const* d_in, const int* in_sizes, int n_in,
                              void* d_out, int out_size, void* d_ws, size_t ws_size,
                              hipStream_t stream)
{
    const float* feat  = (const float*)d_in[0];
    const int*   xnode = (const int*)d_in[1];
    const int*   xneis = (const int*)d_in[2];
    const int*   etype = (const int*)d_in[3];
    const float* dg    = (const float*)d_in[4];
    const float* Hinit = (const float*)d_in[5];
    const float* Wxi   = (const float*)d_in[6];
    const float* bxi   = (const float*)d_in[7];
    const float* Wrou  = (const float*)d_in[8];
    const float* brou  = (const float*)d_in[9];
    const float* W1    = (const float*)d_in[10];
    const float* b1    = (const float*)d_in[11];

    char* ws = (char*)d_ws;
    __hip_bfloat16* A = (__hip_bfloat16*)ws;  ws += (size_t)E * 64 * 2;   // 204.8 MB
    float* bias   = (float*)ws;               ws += (size_t)E * 8 * 4;    // 51.2 MB
    float* B0     = (float*)ws;               ws += (size_t)V * 8 * 4;    // 3.2 MB
    float* B1     = (float*)ws;               ws += (size_t)V * 8 * 4;    // 3.2 MB
    float* logits = (float*)ws;               ws += (size_t)V * 4;        // 0.4 MB
    float* pmax   = (float*)ws;               ws += 256 * 4;
    float* Mp     = (float*)ws;               ws += 16;
    float* accum  = (float*)ws;               ws += 64;                   // 9 used

    precompute_kernel<<<1000, 256, 0, stream>>>(feat, xnode, xneis, etype, dg,
                                                Wxi, bxi, Wrou, brou, A, bias);

    const float* Hcur = Hinit;
    float* bufs[2] = {B0, B1};
    for (int t = 0; t < 4; ++t) {
        float* Hn = bufs[t & 1];
        hipMemsetAsync(Hn, 0, (size_t)V * 8 * 4, stream);
        step_kernel<<<(E + 255) / 256, 256, 0, stream>>>(Hcur, Hn, A, bias, xnode, xneis);
        Hcur = Hn;
    }

    logits_kernel<<<(V + 255) / 256, 256, 0, stream>>>(Hcur, W1, b1, logits);
    reduce_max_kernel<<<256, 256, 0, stream>>>(logits, pmax);
    final_max_kernel<<<1, 256, 0, stream>>>(pmax, Mp);
    hipMemsetAsync(accum, 0, 64, stream);
    sum_kernel<<<256, 256, 0, stream>>>(Hcur, logits, Mp, accum);
    final_kernel<<<1, 64, 0, stream>>>(accum, (float*)d_out);
}

// Round 2
// 928.955 us; speedup vs baseline: 4.2287x; 4.2287x over previous
//
#include <hip/hip_runtime.h>
#include <hip/hip_bf16.h>

constexpr int V   = 100000;
constexpr int E   = 1600000;
constexpr int NET = 10;
constexpr int KXW = 138;            // W_xi row length (2*64+10)
constexpr int NB  = (V + 255) / 256;  // 391 blocks over nodes
constexpr float MUS = 0.1125f;      // MU / S

typedef __attribute__((ext_vector_type(8))) short short8;
typedef __attribute__((ext_vector_type(4))) float float4v;

__device__ __forceinline__ float fast_tanh(float x) {
    return 1.0f - 2.0f / (__expf(2.0f * x) + 1.0f);
}
__device__ __forceinline__ float bflo(unsigned u) { return __uint_as_float(u << 16); }
__device__ __forceinline__ float bfhi(unsigned u) { return __uint_as_float(u & 0xffff0000u); }
__device__ __forceinline__ short f2bf(float x) {
    union { __hip_bfloat16 b; short s; } u; u.b = __float2bfloat16(x); return u.s;
}

// ---------------------------------------------------------------------------
// feat fp32 -> bf16 (for MFMA A-operand gathers)
// ---------------------------------------------------------------------------
__global__ __launch_bounds__(256) void featcvt_kernel(
    const float* __restrict__ feat, ushort* __restrict__ featbf)
{
    int i = blockIdx.x * 256 + threadIdx.x;      // one float4 group
    if (i >= V * 16) return;
    float4 f = ((const float4*)feat)[i];
    ushort4 u;
    u.x = (ushort)f2bf(f.x); u.y = (ushort)f2bf(f.y);
    u.z = (ushort)f2bf(f.z); u.w = (ushort)f2bf(f.w);
    ((ushort4*)featbf)[i] = u;
}

// ---------------------------------------------------------------------------
// CSR build: histogram over RAW 1-indexed X_Neis (drop id >= V)
// ---------------------------------------------------------------------------
__global__ __launch_bounds__(256) void hist_kernel(
    const int* __restrict__ xneis, int* __restrict__ count)
{
    int e = blockIdx.x * 256 + threadIdx.x;
    if (e >= E) return;
    int nr = xneis[e];
    if (nr < V) atomicAdd(&count[nr], 1);
}

__global__ __launch_bounds__(256) void scan_block_kernel(
    const int* __restrict__ count, int* __restrict__ scanned, int* __restrict__ blocksum)
{
    __shared__ int s[256];
    int tid = threadIdx.x;
    int i = blockIdx.x * 256 + tid;
    int v = (i < V) ? count[i] : 0;
    s[tid] = v; __syncthreads();
    #pragma unroll
    for (int off = 1; off < 256; off <<= 1) {
        int t = (tid >= off) ? s[tid - off] : 0;
        __syncthreads();
        s[tid] += t;
        __syncthreads();
    }
    if (i < V) scanned[i] = s[tid] - v;          // block-exclusive
    if (tid == 255) blocksum[blockIdx.x] = s[255];
}

__global__ __launch_bounds__(512) void scan_tops_kernel(
    const int* __restrict__ blocksum, int* __restrict__ tops, int* __restrict__ rowptr)
{
    __shared__ int s[512];
    int tid = threadIdx.x;
    int v = (tid < NB) ? blocksum[tid] : 0;
    s[tid] = v; __syncthreads();
    #pragma unroll
    for (int off = 1; off < 512; off <<= 1) {
        int t = (tid >= off) ? s[tid - off] : 0;
        __syncthreads();
        s[tid] += t;
        __syncthreads();
    }
    if (tid < NB) tops[tid] = s[tid] - v;        // exclusive
    if (tid == 511) rowptr[V] = s[511];          // total kept edges
}

__global__ __launch_bounds__(256) void add_offsets_kernel(
    const int* __restrict__ scanned, const int* __restrict__ tops, int* __restrict__ rowptr)
{
    int i = blockIdx.x * 256 + threadIdx.x;
    if (i < V) rowptr[i] = scanned[i] + tops[blockIdx.x];
}

__global__ __launch_bounds__(256) void scatter_kernel(
    const int* __restrict__ xnode, const int* __restrict__ xneis,
    const int* __restrict__ rowptr, int* __restrict__ cursor,
    int* __restrict__ posof, int* __restrict__ esrc)
{
    int e = blockIdx.x * 256 + threadIdx.x;
    if (e >= E) return;
    int nr = xneis[e];
    if (nr < V) {
        int p = rowptr[nr] + atomicAdd(&cursor[nr], 1);
        posof[e] = p;
        esrc[p] = xnode[e] - 1;
    } else {
        posof[e] = -1;
    }
}

// ---------------------------------------------------------------------------
// Per-node bias sum: all edges into node v share bias = tanh(W_rou·feat[v-1]+b)
// => Bsum[v] = count[v] * tanh(...)
// ---------------------------------------------------------------------------
__global__ __launch_bounds__(256) void bsum_kernel(
    const float* __restrict__ feat, const int* __restrict__ count,
    const float* __restrict__ Wrou, const float* __restrict__ brou,
    float* __restrict__ Bsum)
{
    __shared__ float Wl[512];
    __shared__ float bl[8];
    int tid = threadIdx.x;
    for (int i = tid; i < 512; i += 256) Wl[i] = Wrou[i];
    if (tid < 8) bl[tid] = brou[tid];
    __syncthreads();

    int v = blockIdx.x * 256 + tid;
    if (v >= V) return;
    int c = count[v];
    float out[8] = {0, 0, 0, 0, 0, 0, 0, 0};
    if (c > 0) {                                  // c>0 implies v >= 1
        const float4* f4 = (const float4*)(feat + (size_t)(v - 1) * 64);
        float acc[8];
        #pragma unroll
        for (int s = 0; s < 8; ++s) acc[s] = bl[s];
        #pragma unroll 4
        for (int k = 0; k < 16; ++k) {
            float4 x = f4[k];
            #pragma unroll
            for (int s = 0; s < 8; ++s) {
                const float* w = &Wl[s * 64 + k * 4];
                acc[s] += x.x * w[0] + x.y * w[1] + x.z * w[2] + x.w * w[3];
            }
        }
        float fc = (float)c;
        #pragma unroll
        for (int s = 0; s < 8; ++s) out[s] = fc * fast_tanh(acc[s]);
    }
    float4* O = (float4*)(Bsum + (size_t)v * 8);
    O[0] = make_float4(out[0], out[1], out[2], out[3]);
    O[1] = make_float4(out[4], out[5], out[6], out[7]);
}

// ---------------------------------------------------------------------------
// MFMA precompute: A_e = tanh(concat(feat[src],feat[dst])·Wxi[:, :128]^T
//                             + Wxi[:,128+et] + bxi) * (MUS/dg)
// written bf16 into CSR position posof[e]. 16 edges per wave-tile.
// Layouts (m89/m91-verified): A[m=lane&15][k=quad*8+j], B[k=quad*8+j][n=lane&15],
// D[m=quad*4+reg][n=lane&15].
// ---------------------------------------------------------------------------
__global__ __launch_bounds__(256) void precompute_mfma_kernel(
    const ushort* __restrict__ featbf, const int* __restrict__ xnode,
    const int* __restrict__ xneis, const int* __restrict__ etype,
    const float* __restrict__ dg, const float* __restrict__ Wxi,
    const float* __restrict__ bxi, const int* __restrict__ posof,
    ushort* __restrict__ Acsr)
{
    __shared__ float Wet[NET * 65];   // [et][n], stride 65 to spread banks
    __shared__ float Bx[64];
    int tid = threadIdx.x;
    for (int i = tid; i < NET * 64; i += 256) {
        int et = i >> 6, n = i & 63;
        Wet[et * 65 + n] = Wxi[n * KXW + 128 + et];
    }
    if (tid < 64) Bx[tid] = bxi[tid];

    const int lane = tid & 63, wave = tid >> 6;
    const int quad = lane >> 4, l16 = lane & 15;

    // Wave-invariant B fragments: B[k][n] = Wxi[n][k], bf16
    short8 bfrag[4][4];
    #pragma unroll
    for (int nt = 0; nt < 4; ++nt) {
        #pragma unroll
        for (int ks = 0; ks < 4; ++ks) {
            const float* wp = Wxi + (size_t)(nt * 16 + l16) * KXW + ks * 32 + quad * 8;
            short8 w;
            #pragma unroll
            for (int j = 0; j < 8; ++j) w[j] = f2bf(wp[j]);
            bfrag[nt][ks] = w;
        }
    }
    __syncthreads();

    const int nwaves = gridDim.x * 4;
    for (int t = blockIdx.x * 4 + wave; t < E / 16; t += nwaves) {
        const int e0 = t * 16;
        const int eA = e0 + l16;
        int srcA = xnode[eA] - 1;
        int dstA = xneis[eA] - 1;
        const short8* sp = (const short8*)(featbf + (size_t)srcA * 64);
        const short8* dp = (const short8*)(featbf + (size_t)dstA * 64);
        short8 a0 = sp[quad];          // k 0..31   (src feats)
        short8 a1 = sp[quad + 4];      // k 32..63
        short8 a2 = dp[quad];          // k 64..95  (dst feats)
        short8 a3 = dp[quad + 4];      // k 96..127

        float4v acc[4];
        #pragma unroll
        for (int nt = 0; nt < 4; ++nt) {
            float4v z = {0.f, 0.f, 0.f, 0.f};
            z = __builtin_amdgcn_mfma_f32_16x16x32_bf16(a0, bfrag[nt][0], z, 0, 0, 0);
            z = __builtin_amdgcn_mfma_f32_16x16x32_bf16(a1, bfrag[nt][1], z, 0, 0, 0);
            z = __builtin_amdgcn_mfma_f32_16x16x32_bf16(a2, bfrag[nt][2], z, 0, 0, 0);
            z = __builtin_amdgcn_mfma_f32_16x16x32_bf16(a3, bfrag[nt][3], z, 0, 0, 0);
            acc[nt] = z;
        }

        #pragma unroll
        for (int r = 0; r < 4; ++r) {
            int em = e0 + quad * 4 + r;
            int et = etype[em] - 1;
            float sc = MUS / dg[em];
            int p = posof[em];
            #pragma unroll
            for (int nt = 0; nt < 4; ++nt) {
                int n = nt * 16 + l16;
                float val = acc[nt][r] + Bx[n] + Wet[et * 65 + n];
                val = fast_tanh(val) * sc;
                if (p >= 0) Acsr[(size_t)p * 64 + n] = (ushort)f2bf(val);
            }
        }
    }
}

// ---------------------------------------------------------------------------
// One recurrence step, CSR gather form: H_out[v] = Bsum[v] + sum_p A[p]·H[esrc[p]]
// ---------------------------------------------------------------------------
__global__ __launch_bounds__(256) void step_kernel(
    const float* __restrict__ Hin, float* __restrict__ Hout,
    const ushort* __restrict__ A, const int* __restrict__ esrc,
    const int* __restrict__ rowptr, const float* __restrict__ Bsum)
{
    int v = blockIdx.x * 256 + threadIdx.x;
    if (v >= V) return;
    int p0 = rowptr[v], p1 = rowptr[v + 1];

    const float4* Bs = (const float4*)(Bsum + (size_t)v * 8);
    float4 b0 = Bs[0], b1 = Bs[1];
    float acc[8] = {b0.x, b0.y, b0.z, b0.w, b1.x, b1.y, b1.z, b1.w};

    for (int p = p0; p < p1; ++p) {
        int s = esrc[p];
        const float4* H4 = (const float4*)(Hin + (size_t)s * 8);
        float4 h0 = H4[0], h1 = H4[1];
        float he[8] = {h0.x, h0.y, h0.z, h0.w, h1.x, h1.y, h1.z, h1.w};
        const uint4* A4 = (const uint4*)(A + (size_t)p * 64);
        #pragma unroll
        for (int r = 0; r < 8; ++r) {
            uint4 av = A4[r];
            acc[r] += bflo(av.x) * he[0] + bfhi(av.x) * he[1]
                    + bflo(av.y) * he[2] + bfhi(av.y) * he[3]
                    + bflo(av.z) * he[4] + bfhi(av.z) * he[5]
                    + bflo(av.w) * he[6] + bfhi(av.w) * he[7];
        }
    }
    float4* O = (float4*)(Hout + (size_t)v * 8);
    O[0] = make_float4(acc[0], acc[1], acc[2], acc[3]);
    O[1] = make_float4(acc[4], acc[5], acc[6], acc[7]);
}

// ---------------------------------------------------------------------------
// Epilogue (unchanged from round 1)
// ---------------------------------------------------------------------------
__global__ __launch_bounds__(256) void logits_kernel(
    const float* __restrict__ H, const float* __restrict__ W1,
    const float* __restrict__ b1, float* __restrict__ logits)
{
    int v = blockIdx.x * 256 + threadIdx.x;
    if (v >= V) return;
    float4 w0 = ((const float4*)W1)[0], w1 = ((const float4*)W1)[1];
    const float4* H4 = (const float4*)(H + (size_t)v * 8);
    float4 h0 = H4[0], h1 = H4[1];
    logits[v] = b1[0]
              + h0.x * w0.x + h0.y * w0.y + h0.z * w0.z + h0.w * w0.w
              + h1.x * w1.x + h1.y * w1.y + h1.z * w1.z + h1.w * w1.w;
}

__global__ __launch_bounds__(256) void reduce_max_kernel(
    const float* __restrict__ logits, float* __restrict__ partial)
{
    float m = -INFINITY;
    for (int v = blockIdx.x * 256 + threadIdx.x; v < V; v += 256 * 256)
        m = fmaxf(m, logits[v]);
    #pragma unroll
    for (int o = 32; o > 0; o >>= 1) m = fmaxf(m, __shfl_down(m, o));
    __shared__ float sm[4];
    if ((threadIdx.x & 63) == 0) sm[threadIdx.x >> 6] = m;
    __syncthreads();
    if (threadIdx.x == 0)
        partial[blockIdx.x] = fmaxf(fmaxf(sm[0], sm[1]), fmaxf(sm[2], sm[3]));
}

__global__ __launch_bounds__(256) void final_max_kernel(
    const float* __restrict__ partial, float* __restrict__ M)
{
    float m = partial[threadIdx.x];
    #pragma unroll
    for (int o = 32; o > 0; o >>= 1) m = fmaxf(m, __shfl_down(m, o));
    __shared__ float sm[4];
    if ((threadIdx.x & 63) == 0) sm[threadIdx.x >> 6] = m;
    __syncthreads();
    if (threadIdx.x == 0) *M = fmaxf(fmaxf(sm[0], sm[1]), fmaxf(sm[2], sm[3]));
}

__global__ __launch_bounds__(256) void sum_kernel(
    const float* __restrict__ H, const float* __restrict__ logits,
    const float* __restrict__ Mp, float* __restrict__ accum)
{
    const float M = *Mp;
    float se = 0.0f;
    float sh[8] = {0, 0, 0, 0, 0, 0, 0, 0};
    for (int v = blockIdx.x * 256 + threadIdx.x; v < V; v += 256 * 256) {
        float w = __expf(logits[v] - M);
        se += w;
        const float4* H4 = (const float4*)(H + (size_t)v * 8);
        float4 h0 = H4[0], h1 = H4[1];
        sh[0] += w * h0.x; sh[1] += w * h0.y; sh[2] += w * h0.z; sh[3] += w * h0.w;
        sh[4] += w * h1.x; sh[5] += w * h1.y; sh[6] += w * h1.z; sh[7] += w * h1.w;
    }
    #pragma unroll
    for (int o = 32; o > 0; o >>= 1) {
        se += __shfl_down(se, o);
        #pragma unroll
        for (int i = 0; i < 8; ++i) sh[i] += __shfl_down(sh[i], o);
    }
    if ((threadIdx.x & 63) == 0) {
        atomicAdd(&accum[8], se);
        #pragma unroll
        for (int i = 0; i < 8; ++i) atomicAdd(&accum[i], sh[i]);
    }
}

__global__ void final_kernel(const float* __restrict__ accum, float* __restrict__ out)
{
    if (threadIdx.x < 8) out[threadIdx.x] = tanhf(accum[threadIdx.x] / accum[8]);
}

// ---------------------------------------------------------------------------
extern "C" void kernel_launch(void* const* d_in, const int* in_sizes, int n_in,
                              void* d_out, int out_size, void* d_ws, size_t ws_size,
                              hipStream_t stream)
{
    const float* feat  = (const float*)d_in[0];
    const int*   xnode = (const int*)d_in[1];
    const int*   xneis = (const int*)d_in[2];
    const int*   etype = (const int*)d_in[3];
    const float* dg    = (const float*)d_in[4];
    const float* Hinit = (const float*)d_in[5];
    const float* Wxi   = (const float*)d_in[6];
    const float* bxi   = (const float*)d_in[7];
    const float* Wrou  = (const float*)d_in[8];
    const float* brou  = (const float*)d_in[9];
    const float* W1    = (const float*)d_in[10];
    const float* b1    = (const float*)d_in[11];

    char* ws = (char*)d_ws;
    auto alloc = [&](size_t bytes) -> char* {
        char* p = ws; ws += (bytes + 255) & ~(size_t)255; return p;
    };
    ushort* Acsr    = (ushort*)alloc((size_t)E * 64 * 2);   // 204.8 MB
    ushort* featbf  = (ushort*)alloc((size_t)V * 64 * 2);   // 12.8 MB
    float*  B0      = (float*)alloc((size_t)V * 8 * 4);
    float*  B1      = (float*)alloc((size_t)V * 8 * 4);
    float*  Bsum    = (float*)alloc((size_t)V * 8 * 4);
    int*    posof   = (int*)alloc((size_t)E * 4);
    int*    esrc    = (int*)alloc((size_t)E * 4);
    int*    count   = (int*)alloc((size_t)2 * V * 4);       // count + cursor (one memset)
    int*    cursor  = count + V;
    int*    scanned = (int*)alloc((size_t)V * 4);
    int*    rowptr  = (int*)alloc((size_t)(V + 1) * 4);
    int*    blocksum= (int*)alloc(512 * 4);
    int*    tops    = (int*)alloc(512 * 4);
    float*  logits  = (float*)alloc((size_t)V * 4);
    float*  pmax    = (float*)alloc(256 * 4);
    float*  Mp      = (float*)alloc(16);
    float*  accum   = (float*)alloc(64);

    featcvt_kernel<<<(V * 16 + 255) / 256, 256, 0, stream>>>(feat, featbf);
    hipMemsetAsync(count, 0, (size_t)2 * V * 4, stream);
    hist_kernel<<<(E + 255) / 256, 256, 0, stream>>>(xneis, count);
    scan_block_kernel<<<NB, 256, 0, stream>>>(count, scanned, blocksum);
    scan_tops_kernel<<<1, 512, 0, stream>>>(blocksum, tops, rowptr);
    add_offsets_kernel<<<NB, 256, 0, stream>>>(scanned, tops, rowptr);
    scatter_kernel<<<(E + 255) / 256, 256, 0, stream>>>(xnode, xneis, rowptr, cursor, posof, esrc);
    bsum_kernel<<<NB, 256, 0, stream>>>(feat, count, Wrou, brou, Bsum);
    precompute_mfma_kernel<<<1024, 256, 0, stream>>>(featbf, xnode, xneis, etype,
                                                     dg, Wxi, bxi, posof, Acsr);

    const float* Hcur = Hinit;
    float* bufs[2] = {B0, B1};
    for (int t = 0; t < 4; ++t) {
        float* Hn = bufs[t & 1];
        step_kernel<<<NB, 256, 0, stream>>>(Hcur, Hn, Acsr, esrc, rowptr, Bsum);
        Hcur = Hn;
    }

    logits_kernel<<<NB, 256, 0, stream>>>(Hcur, W1, b1, logits);
    reduce_max_kernel<<<256, 256, 0, stream>>>(logits, pmax);
    final_max_kernel<<<1, 256, 0, stream>>>(pmax, Mp);
    hipMemsetAsync(accum, 0, 64, stream);
    sum_kernel<<<256, 256, 0, stream>>>(Hcur, logits, Mp, accum);
    final_kernel<<<1, 64, 0, stream>>>(accum, (float*)d_out);
}

// Round 4
// 805.101 us; speedup vs baseline: 4.8792x; 1.1538x over previous
//
#include <hip/hip_runtime.h>
#include <hip/hip_bf16.h>

constexpr int V   = 100000;
constexpr int E   = 1600000;
constexpr int NET = 10;
constexpr int KXW = 138;              // W_xi row length (2*64+10)
constexpr int NB  = (V + 255) / 256;  // 391 blocks over nodes
constexpr float MUS = 0.1125f;        // MU / S

typedef __attribute__((ext_vector_type(8))) short short8;
typedef __attribute__((ext_vector_type(4))) float float4v;

__device__ __forceinline__ float fast_tanh(float x) {
    return 1.0f - 2.0f / (__expf(2.0f * x) + 1.0f);
}
__device__ __forceinline__ float bflo(unsigned u) { return __uint_as_float(u << 16); }
__device__ __forceinline__ float bfhi(unsigned u) { return __uint_as_float(u & 0xffff0000u); }
__device__ __forceinline__ short f2bf(float x) {
    union { __hip_bfloat16 b; short s; } u; u.b = __float2bfloat16(x); return u.s;
}

// ---------------------------------------------------------------------------
// CSR build: histogram over RAW 1-indexed X_Neis (drop id >= V)
// ---------------------------------------------------------------------------
__global__ __launch_bounds__(256) void hist_kernel(
    const int* __restrict__ xneis, int* __restrict__ count)
{
    int e = blockIdx.x * 256 + threadIdx.x;
    if (e >= E) return;
    int nr = xneis[e];
    if (nr < V) atomicAdd(&count[nr], 1);
}

__global__ __launch_bounds__(256) void scan_block_kernel(
    const int* __restrict__ count, int* __restrict__ scanned, int* __restrict__ blocksum)
{
    __shared__ int s[256];
    int tid = threadIdx.x;
    int i = blockIdx.x * 256 + tid;
    int v = (i < V) ? count[i] : 0;
    s[tid] = v; __syncthreads();
    #pragma unroll
    for (int off = 1; off < 256; off <<= 1) {
        int t = (tid >= off) ? s[tid - off] : 0;
        __syncthreads();
        s[tid] += t;
        __syncthreads();
    }
    if (i < V) scanned[i] = s[tid] - v;          // block-exclusive
    if (tid == 255) blocksum[blockIdx.x] = s[255];
}

__global__ __launch_bounds__(512) void scan_tops_kernel(
    const int* __restrict__ blocksum, int* __restrict__ tops, int* __restrict__ rowptr)
{
    __shared__ int s[512];
    int tid = threadIdx.x;
    int v = (tid < NB) ? blocksum[tid] : 0;
    s[tid] = v; __syncthreads();
    #pragma unroll
    for (int off = 1; off < 512; off <<= 1) {
        int t = (tid >= off) ? s[tid - off] : 0;
        __syncthreads();
        s[tid] += t;
        __syncthreads();
    }
    if (tid < NB) tops[tid] = s[tid] - v;        // exclusive
    if (tid == 511) rowptr[V] = s[511];          // total kept edges
}

__global__ __launch_bounds__(256) void add_offsets_kernel(
    const int* __restrict__ scanned, const int* __restrict__ tops, int* __restrict__ rowptr)
{
    int i = blockIdx.x * 256 + threadIdx.x;
    if (i < V) rowptr[i] = scanned[i] + tops[blockIdx.x];
}

__global__ __launch_bounds__(256) void scatter_kernel(
    const int* __restrict__ xnode, const int* __restrict__ xneis,
    const int* __restrict__ rowptr, int* __restrict__ cursor,
    int* __restrict__ posof, int* __restrict__ esrc)
{
    int e = blockIdx.x * 256 + threadIdx.x;
    if (e >= E) return;
    int nr = xneis[e];
    if (nr < V) {
        int p = rowptr[nr] + atomicAdd(&cursor[nr], 1);
        posof[e] = p;
        esrc[p] = xnode[e] - 1;
    } else {
        posof[e] = -1;
    }
}

// ---------------------------------------------------------------------------
// Per-node bias sum: Bsum[v] = count[v] * tanh(W_rou·feat[v-1]+b)
// ---------------------------------------------------------------------------
__global__ __launch_bounds__(256) void bsum_kernel(
    const float* __restrict__ feat, const int* __restrict__ count,
    const float* __restrict__ Wrou, const float* __restrict__ brou,
    float* __restrict__ Bsum)
{
    __shared__ float Wl[512];
    __shared__ float bl[8];
    int tid = threadIdx.x;
    for (int i = tid; i < 512; i += 256) Wl[i] = Wrou[i];
    if (tid < 8) bl[tid] = brou[tid];
    __syncthreads();

    int v = blockIdx.x * 256 + tid;
    if (v >= V) return;
    int c = count[v];
    float out[8] = {0, 0, 0, 0, 0, 0, 0, 0};
    if (c > 0) {                                  // c>0 implies v >= 1
        const float4* f4 = (const float4*)(feat + (size_t)(v - 1) * 64);
        float acc[8];
        #pragma unroll
        for (int s = 0; s < 8; ++s) acc[s] = bl[s];
        #pragma unroll 4
        for (int k = 0; k < 16; ++k) {
            float4 x = f4[k];
            #pragma unroll
            for (int s = 0; s < 8; ++s) {
                const float* w = &Wl[s * 64 + k * 4];
                acc[s] += x.x * w[0] + x.y * w[1] + x.z * w[2] + x.w * w[3];
            }
        }
        float fc = (float)c;
        #pragma unroll
        for (int s = 0; s < 8; ++s) out[s] = fc * fast_tanh(acc[s]);
    }
    float4* O = (float4*)(Bsum + (size_t)v * 8);
    O[0] = make_float4(out[0], out[1], out[2], out[3]);
    O[1] = make_float4(out[4], out[5], out[6], out[7]);
}

// ---------------------------------------------------------------------------
// PQ GEMM (MFMA): PQ[v][0:64] = feat[v]·Wxi[:, 0:64]^T   (P part)
//                 PQ[v][64:128] = feat[v]·Wxi[:, 64:128]^T (Q part), bf16 out
// ---------------------------------------------------------------------------
__global__ __launch_bounds__(256) void pq_kernel(
    const float* __restrict__ feat, const float* __restrict__ Wxi,
    ushort* __restrict__ PQ)
{
    const int lane = threadIdx.x & 63, wave = threadIdx.x >> 6;
    const int quad = lane >> 4, l16 = lane & 15;

    // B fragments: B[k][n] = Wxi[n][k] (P) and Wxi[n][64+k] (Q), k=quad*8+j+32*ks
    short8 bP[4][2], bQ[4][2];
    #pragma unroll
    for (int nt = 0; nt < 4; ++nt) {
        #pragma unroll
        for (int ks = 0; ks < 2; ++ks) {
            const float* wp = Wxi + (size_t)(nt * 16 + l16) * KXW + ks * 32 + quad * 8;
            short8 p, q;
            #pragma unroll
            for (int j = 0; j < 8; ++j) { p[j] = f2bf(wp[j]); q[j] = f2bf(wp[64 + j]); }
            bP[nt][ks] = p; bQ[nt][ks] = q;
        }
    }

    int t = blockIdx.x * 4 + wave;
    if (t >= V / 16) return;
    int v0 = t * 16;

    const float* fp = feat + (size_t)(v0 + l16) * 64 + quad * 8;
    short8 a0, a1;
    #pragma unroll
    for (int j = 0; j < 8; ++j) { a0[j] = f2bf(fp[j]); a1[j] = f2bf(fp[32 + j]); }

    float4v accP[4], accQ[4];
    #pragma unroll
    for (int nt = 0; nt < 4; ++nt) {
        float4v z = {0.f, 0.f, 0.f, 0.f};
        z = __builtin_amdgcn_mfma_f32_16x16x32_bf16(a0, bP[nt][0], z, 0, 0, 0);
        z = __builtin_amdgcn_mfma_f32_16x16x32_bf16(a1, bP[nt][1], z, 0, 0, 0);
        accP[nt] = z;
        float4v w = {0.f, 0.f, 0.f, 0.f};
        w = __builtin_amdgcn_mfma_f32_16x16x32_bf16(a0, bQ[nt][0], w, 0, 0, 0);
        w = __builtin_amdgcn_mfma_f32_16x16x32_bf16(a1, bQ[nt][1], w, 0, 0, 0);
        accQ[nt] = w;
    }

    #pragma unroll
    for (int r = 0; r < 4; ++r) {
        ushort* row = PQ + (size_t)(v0 + quad * 4 + r) * 128;
        #pragma unroll
        for (int nt = 0; nt < 4; ++nt) {
            row[nt * 16 + l16]      = (ushort)f2bf(accP[nt][r]);
            row[64 + nt * 16 + l16] = (ushort)f2bf(accQ[nt][r]);
        }
    }
}

// ---------------------------------------------------------------------------
// Edge kernel (streaming): A_e = tanh(P[src]+Q[dst]+Wet[et]+bxi)·(MUS/dg)
// 16 lanes per edge, bf16 write into CSR slot posof[e].
// ---------------------------------------------------------------------------
__global__ __launch_bounds__(256) void edge_kernel(
    const int* __restrict__ xnode, const int* __restrict__ xneis,
    const int* __restrict__ etype, const float* __restrict__ dg,
    const int* __restrict__ posof, const ushort* __restrict__ PQ,
    const float* __restrict__ Wxi, const float* __restrict__ bxi,
    ushort* __restrict__ Acsr)
{
    __shared__ float WetB[NET * 64];
    int tid = threadIdx.x;
    for (int i = tid; i < NET * 64; i += 256) {
        int et = i >> 6, n = i & 63;
        WetB[i] = Wxi[n * KXW + 128 + et] + bxi[n];
    }
    __syncthreads();

    size_t g = (size_t)blockIdx.x * 256 + tid;
    int e = (int)(g >> 4), l = (int)(g & 15);
    if (e >= E) return;
    int p = posof[e];
    if (p < 0) return;

    int src = xnode[e] - 1;
    int dst = xneis[e] - 1;
    int et  = etype[e] - 1;
    float sc = MUS / dg[e];

    uint2 pu = *(const uint2*)(PQ + (size_t)src * 128 + l * 4);
    uint2 qu = *(const uint2*)(PQ + (size_t)dst * 128 + 64 + l * 4);
    float4 wb = *(const float4*)(WetB + et * 64 + l * 4);

    float v0 = bflo(pu.x) + bflo(qu.x) + wb.x;
    float v1 = bfhi(pu.x) + bfhi(qu.x) + wb.y;
    float v2 = bflo(pu.y) + bflo(qu.y) + wb.z;
    float v3 = bfhi(pu.y) + bfhi(qu.y) + wb.w;

    ushort4 o;
    o.x = (ushort)f2bf(fast_tanh(v0) * sc);
    o.y = (ushort)f2bf(fast_tanh(v1) * sc);
    o.z = (ushort)f2bf(fast_tanh(v2) * sc);
    o.w = (ushort)f2bf(fast_tanh(v3) * sc);
    *(ushort4*)(Acsr + (size_t)p * 64 + l * 4) = o;
}

// ---------------------------------------------------------------------------
// One recurrence step, 8 lanes per node: lane s computes H_out[v][s]
// ---------------------------------------------------------------------------
__global__ __launch_bounds__(256) void step_kernel(
    const float* __restrict__ Hin, float* __restrict__ Hout,
    const ushort* __restrict__ A, const int* __restrict__ esrc,
    const int* __restrict__ rowptr, const float* __restrict__ Bsum)
{
    int g = blockIdx.x * 256 + threadIdx.x;
    int v = g >> 3, s = g & 7;
    if (v >= V) return;
    int p0 = rowptr[v], p1 = rowptr[v + 1];

    float acc = Bsum[(size_t)v * 8 + s];
    for (int p = p0; p < p1; ++p) {
        int src = esrc[p];
        const float4* H4 = (const float4*)(Hin + (size_t)src * 8);
        float4 h0 = H4[0], h1 = H4[1];
        uint4 av = *(const uint4*)(A + (size_t)p * 64 + s * 8);
        acc += bflo(av.x) * h0.x + bfhi(av.x) * h0.y
             + bflo(av.y) * h0.z + bfhi(av.y) * h0.w
             + bflo(av.z) * h1.x + bfhi(av.z) * h1.y
             + bflo(av.w) * h1.z + bfhi(av.w) * h1.w;
    }
    Hout[(size_t)v * 8 + s] = acc;
}

// ---------------------------------------------------------------------------
// Epilogue
// ---------------------------------------------------------------------------
__global__ __launch_bounds__(256) void logits_kernel(
    const float* __restrict__ H, const float* __restrict__ W1,
    const float* __restrict__ b1, float* __restrict__ logits)
{
    int v = blockIdx.x * 256 + threadIdx.x;
    if (v >= V) return;
    float4 w0 = ((const float4*)W1)[0], w1 = ((const float4*)W1)[1];
    const float4* H4 = (const float4*)(H + (size_t)v * 8);
    float4 h0 = H4[0], h1 = H4[1];
    logits[v] = b1[0]
              + h0.x * w0.x + h0.y * w0.y + h0.z * w0.z + h0.w * w0.w
              + h1.x * w1.x + h1.y * w1.y + h1.z * w1.z + h1.w * w1.w;
}

__global__ __launch_bounds__(256) void reduce_max_kernel(
    const float* __restrict__ logits, float* __restrict__ partial)
{
    float m = -INFINITY;
    for (int v = blockIdx.x * 256 + threadIdx.x; v < V; v += 256 * 256)
        m = fmaxf(m, logits[v]);
    #pragma unroll
    for (int o = 32; o > 0; o >>= 1) m = fmaxf(m, __shfl_down(m, o));
    __shared__ float sm[4];
    if ((threadIdx.x & 63) == 0) sm[threadIdx.x >> 6] = m;
    __syncthreads();
    if (threadIdx.x == 0)
        partial[blockIdx.x] = fmaxf(fmaxf(sm[0], sm[1]), fmaxf(sm[2], sm[3]));
}

__global__ __launch_bounds__(256) void final_max_kernel(
    const float* __restrict__ partial, float* __restrict__ M)
{
    float m = partial[threadIdx.x];
    #pragma unroll
    for (int o = 32; o > 0; o >>= 1) m = fmaxf(m, __shfl_down(m, o));
    __shared__ float sm[4];
    if ((threadIdx.x & 63) == 0) sm[threadIdx.x >> 6] = m;
    __syncthreads();
    if (threadIdx.x == 0) *M = fmaxf(fmaxf(sm[0], sm[1]), fmaxf(sm[2], sm[3]));
}

__global__ __launch_bounds__(256) void sum_kernel(
    const float* __restrict__ H, const float* __restrict__ logits,
    const float* __restrict__ Mp, float* __restrict__ accum)
{
    const float M = *Mp;
    float se = 0.0f;
    float sh[8] = {0, 0, 0, 0, 0, 0, 0, 0};
    for (int v = blockIdx.x * 256 + threadIdx.x; v < V; v += 256 * 256) {
        float w = __expf(logits[v] - M);
        se += w;
        const float4* H4 = (const float4*)(H + (size_t)v * 8);
        float4 h0 = H4[0], h1 = H4[1];
        sh[0] += w * h0.x; sh[1] += w * h0.y; sh[2] += w * h0.z; sh[3] += w * h0.w;
        sh[4] += w * h1.x; sh[5] += w * h1.y; sh[6] += w * h1.z; sh[7] += w * h1.w;
    }
    #pragma unroll
    for (int o = 32; o > 0; o >>= 1) {
        se += __shfl_down(se, o);
        #pragma unroll
        for (int i = 0; i < 8; ++i) sh[i] += __shfl_down(sh[i], o);
    }
    if ((threadIdx.x & 63) == 0) {
        atomicAdd(&accum[8], se);
        #pragma unroll
        for (int i = 0; i < 8; ++i) atomicAdd(&accum[i], sh[i]);
    }
}

__global__ void final_kernel(const float* __restrict__ accum, float* __restrict__ out)
{
    if (threadIdx.x < 8) out[threadIdx.x] = tanhf(accum[threadIdx.x] / accum[8]);
}

// ---------------------------------------------------------------------------
extern "C" void kernel_launch(void* const* d_in, const int* in_sizes, int n_in,
                              void* d_out, int out_size, void* d_ws, size_t ws_size,
                              hipStream_t stream)
{
    const float* feat  = (const float*)d_in[0];
    const int*   xnode = (const int*)d_in[1];
    const int*   xneis = (const int*)d_in[2];
    const int*   etype = (const int*)d_in[3];
    const float* dg    = (const float*)d_in[4];
    const float* Hinit = (const float*)d_in[5];
    const float* Wxi   = (const float*)d_in[6];
    const float* bxi   = (const float*)d_in[7];
    const float* Wrou  = (const float*)d_in[8];
    const float* brou  = (const float*)d_in[9];
    const float* W1    = (const float*)d_in[10];
    const float* b1    = (const float*)d_in[11];

    char* ws = (char*)d_ws;
    auto alloc = [&](size_t bytes) -> char* {
        char* p = ws; ws += (bytes + 255) & ~(size_t)255; return p;
    };
    // Budget (ws_size is ~256 MiB): total ≈ 255.3 MB
    ushort* Acsr    = (ushort*)alloc((size_t)E * 64 * 2);     // 204.8 MB
    ushort* PQ      = (ushort*)alloc((size_t)V * 128 * 2);    // 25.6 MB (bf16)
    float*  B0      = (float*)alloc((size_t)V * 8 * 4);       // 3.2 MB
    float*  B1      = (float*)alloc((size_t)V * 8 * 4);       // 3.2 MB
    float*  Bsum    = (float*)alloc((size_t)V * 8 * 4);       // 3.2 MB
    int*    posof   = (int*)alloc((size_t)E * 4);             // 6.4 MB
    int*    esrc    = (int*)alloc((size_t)E * 4);             // 6.4 MB
    int*    count   = (int*)alloc((size_t)2 * V * 4);         // 0.8 MB (count+cursor)
    int*    cursor  = count + V;
    int*    scanned = (int*)alloc((size_t)V * 4);             // 0.4 MB
    int*    rowptr  = (int*)alloc((size_t)(V + 1) * 4);       // 0.4 MB
    int*    blocksum= (int*)alloc(512 * 4);
    int*    tops    = (int*)alloc(512 * 4);
    float*  logits  = (float*)alloc((size_t)V * 4);           // 0.4 MB
    float*  pmax    = (float*)alloc(256 * 4);
    float*  Mp      = (float*)alloc(16);
    float*  accum   = (float*)alloc(64);

    hipMemsetAsync(count, 0, (size_t)2 * V * 4, stream);
    hist_kernel<<<(E + 255) / 256, 256, 0, stream>>>(xneis, count);
    scan_block_kernel<<<NB, 256, 0, stream>>>(count, scanned, blocksum);
    scan_tops_kernel<<<1, 512, 0, stream>>>(blocksum, tops, rowptr);
    add_offsets_kernel<<<NB, 256, 0, stream>>>(scanned, tops, rowptr);
    scatter_kernel<<<(E + 255) / 256, 256, 0, stream>>>(xnode, xneis, rowptr, cursor, posof, esrc);
    pq_kernel<<<(V / 16 + 3) / 4, 256, 0, stream>>>(feat, Wxi, PQ);
    bsum_kernel<<<NB, 256, 0, stream>>>(feat, count, Wrou, brou, Bsum);
    edge_kernel<<<(int)(((size_t)E * 16 + 255) / 256), 256, 0, stream>>>(
        xnode, xneis, etype, dg, posof, PQ, Wxi, bxi, Acsr);

    const float* Hcur = Hinit;
    float* bufs[2] = {B0, B1};
    for (int t = 0; t < 4; ++t) {
        float* Hn = bufs[t & 1];
        step_kernel<<<(V * 8 + 255) / 256, 256, 0, stream>>>(Hcur, Hn, Acsr, esrc, rowptr, Bsum);
        Hcur = Hn;
    }

    logits_kernel<<<NB, 256, 0, stream>>>(Hcur, W1, b1, logits);
    reduce_max_kernel<<<256, 256, 0, stream>>>(logits, pmax);
    final_max_kernel<<<1, 256, 0, stream>>>(pmax, Mp);
    hipMemsetAsync(accum, 0, 64, stream);
    sum_kernel<<<256, 256, 0, stream>>>(Hcur, logits, Mp, accum);
    final_kernel<<<1, 64, 0, stream>>>(accum, (float*)d_out);
}

// Round 6
// 792.648 us; speedup vs baseline: 4.9559x; 1.0157x over previous
//
#include <hip/hip_runtime.h>
#include <hip/hip_bf16.h>

constexpr int V   = 100000;
constexpr int E   = 1600000;
constexpr int NET = 10;
constexpr int KXW = 138;              // W_xi row length (2*64+10)
constexpr int NB  = (V + 255) / 256;  // 391 blocks over nodes
constexpr float MUS = 0.1125f;        // MU / S

typedef __attribute__((ext_vector_type(8))) short short8;
typedef __attribute__((ext_vector_type(4))) float float4v;
typedef __attribute__((ext_vector_type(2))) unsigned int uint2v;  // for nontemporal store

__device__ __forceinline__ float fast_tanh(float x) {
    return 1.0f - 2.0f / (__expf(2.0f * x) + 1.0f);
}
__device__ __forceinline__ float bflo(unsigned u) { return __uint_as_float(u << 16); }
__device__ __forceinline__ float bfhi(unsigned u) { return __uint_as_float(u & 0xffff0000u); }
__device__ __forceinline__ short f2bf(float x) {
    union { __hip_bfloat16 b; short s; } u; u.b = __float2bfloat16(x); return u.s;
}

// ---------------------------------------------------------------------------
// CSR build: histogram over RAW 1-indexed X_Neis (drop id >= V)
// ---------------------------------------------------------------------------
__global__ __launch_bounds__(256) void hist_kernel(
    const int* __restrict__ xneis, int* __restrict__ count)
{
    int e = blockIdx.x * 256 + threadIdx.x;
    if (e >= E) return;
    int nr = xneis[e];
    if (nr < V) atomicAdd(&count[nr], 1);
}

__global__ __launch_bounds__(256) void scan_block_kernel(
    const int* __restrict__ count, int* __restrict__ scanned, int* __restrict__ blocksum)
{
    __shared__ int s[256];
    int tid = threadIdx.x;
    int i = blockIdx.x * 256 + tid;
    int v = (i < V) ? count[i] : 0;
    s[tid] = v; __syncthreads();
    #pragma unroll
    for (int off = 1; off < 256; off <<= 1) {
        int t = (tid >= off) ? s[tid - off] : 0;
        __syncthreads();
        s[tid] += t;
        __syncthreads();
    }
    if (i < V) scanned[i] = s[tid] - v;          // block-exclusive
    if (tid == 255) blocksum[blockIdx.x] = s[255];
}

__global__ __launch_bounds__(512) void scan_tops_kernel(
    const int* __restrict__ blocksum, int* __restrict__ tops, int* __restrict__ rowptr)
{
    __shared__ int s[512];
    int tid = threadIdx.x;
    int v = (tid < NB) ? blocksum[tid] : 0;
    s[tid] = v; __syncthreads();
    #pragma unroll
    for (int off = 1; off < 512; off <<= 1) {
        int t = (tid >= off) ? s[tid - off] : 0;
        __syncthreads();
        s[tid] += t;
        __syncthreads();
    }
    if (tid < NB) tops[tid] = s[tid] - v;        // exclusive
    if (tid == 511) rowptr[V] = s[511];          // total kept edges
}

__global__ __launch_bounds__(256) void add_offsets_kernel(
    const int* __restrict__ scanned, const int* __restrict__ tops, int* __restrict__ rowptr)
{
    int i = blockIdx.x * 256 + threadIdx.x;
    if (i < V) rowptr[i] = scanned[i] + tops[blockIdx.x];
}

__global__ __launch_bounds__(256) void scatter_kernel(
    const int* __restrict__ xnode, const int* __restrict__ xneis,
    const int* __restrict__ rowptr, int* __restrict__ cursor,
    int* __restrict__ posof, int* __restrict__ esrc)
{
    int e = blockIdx.x * 256 + threadIdx.x;
    if (e >= E) return;
    int nr = xneis[e];
    if (nr < V) {
        int p = rowptr[nr] + atomicAdd(&cursor[nr], 1);
        posof[e] = p;
        esrc[p] = xnode[e] - 1;
    } else {
        posof[e] = -1;
    }
}

// ---------------------------------------------------------------------------
// Per-node bias sum: Bsum[v] = count[v] * tanh(W_rou·feat[v-1]+b)
// ---------------------------------------------------------------------------
__global__ __launch_bounds__(256) void bsum_kernel(
    const float* __restrict__ feat, const int* __restrict__ count,
    const float* __restrict__ Wrou, const float* __restrict__ brou,
    float* __restrict__ Bsum)
{
    __shared__ float Wl[512];
    __shared__ float bl[8];
    int tid = threadIdx.x;
    for (int i = tid; i < 512; i += 256) Wl[i] = Wrou[i];
    if (tid < 8) bl[tid] = brou[tid];
    __syncthreads();

    int v = blockIdx.x * 256 + tid;
    if (v >= V) return;
    int c = count[v];
    float out[8] = {0, 0, 0, 0, 0, 0, 0, 0};
    if (c > 0) {                                  // c>0 implies v >= 1
        const float4* f4 = (const float4*)(feat + (size_t)(v - 1) * 64);
        float acc[8];
        #pragma unroll
        for (int s = 0; s < 8; ++s) acc[s] = bl[s];
        #pragma unroll 4
        for (int k = 0; k < 16; ++k) {
            float4 x = f4[k];
            #pragma unroll
            for (int s = 0; s < 8; ++s) {
                const float* w = &Wl[s * 64 + k * 4];
                acc[s] += x.x * w[0] + x.y * w[1] + x.z * w[2] + x.w * w[3];
            }
        }
        float fc = (float)c;
        #pragma unroll
        for (int s = 0; s < 8; ++s) out[s] = fc * fast_tanh(acc[s]);
    }
    float4* O = (float4*)(Bsum + (size_t)v * 8);
    O[0] = make_float4(out[0], out[1], out[2], out[3]);
    O[1] = make_float4(out[4], out[5], out[6], out[7]);
}

// ---------------------------------------------------------------------------
// PQ GEMM (MFMA): PQ[v][0:64] = feat[v]·Wxi[:, 0:64]^T   (P part)
//                 PQ[v][64:128] = feat[v]·Wxi[:, 64:128]^T (Q part), bf16 out
// ---------------------------------------------------------------------------
__global__ __launch_bounds__(256) void pq_kernel(
    const float* __restrict__ feat, const float* __restrict__ Wxi,
    ushort* __restrict__ PQ)
{
    const int lane = threadIdx.x & 63, wave = threadIdx.x >> 6;
    const int quad = lane >> 4, l16 = lane & 15;

    short8 bP[4][2], bQ[4][2];
    #pragma unroll
    for (int nt = 0; nt < 4; ++nt) {
        #pragma unroll
        for (int ks = 0; ks < 2; ++ks) {
            const float* wp = Wxi + (size_t)(nt * 16 + l16) * KXW + ks * 32 + quad * 8;
            short8 p, q;
            #pragma unroll
            for (int j = 0; j < 8; ++j) { p[j] = f2bf(wp[j]); q[j] = f2bf(wp[64 + j]); }
            bP[nt][ks] = p; bQ[nt][ks] = q;
        }
    }

    int t = blockIdx.x * 4 + wave;
    if (t >= V / 16) return;
    int v0 = t * 16;

    const float* fp = feat + (size_t)(v0 + l16) * 64 + quad * 8;
    short8 a0, a1;
    #pragma unroll
    for (int j = 0; j < 8; ++j) { a0[j] = f2bf(fp[j]); a1[j] = f2bf(fp[32 + j]); }

    float4v accP[4], accQ[4];
    #pragma unroll
    for (int nt = 0; nt < 4; ++nt) {
        float4v z = {0.f, 0.f, 0.f, 0.f};
        z = __builtin_amdgcn_mfma_f32_16x16x32_bf16(a0, bP[nt][0], z, 0, 0, 0);
        z = __builtin_amdgcn_mfma_f32_16x16x32_bf16(a1, bP[nt][1], z, 0, 0, 0);
        accP[nt] = z;
        float4v w = {0.f, 0.f, 0.f, 0.f};
        w = __builtin_amdgcn_mfma_f32_16x16x32_bf16(a0, bQ[nt][0], w, 0, 0, 0);
        w = __builtin_amdgcn_mfma_f32_16x16x32_bf16(a1, bQ[nt][1], w, 0, 0, 0);
        accQ[nt] = w;
    }

    #pragma unroll
    for (int r = 0; r < 4; ++r) {
        ushort* row = PQ + (size_t)(v0 + quad * 4 + r) * 128;
        #pragma unroll
        for (int nt = 0; nt < 4; ++nt) {
            row[nt * 16 + l16]      = (ushort)f2bf(accP[nt][r]);
            row[64 + nt * 16 + l16] = (ushort)f2bf(accQ[nt][r]);
        }
    }
}

// ---------------------------------------------------------------------------
// Edge kernel (streaming): A_e = tanh(P[src]+Q[dst]+Wet[et]+bxi)·(MUS/dg)
// 16 lanes per edge, bf16 write into CSR slot posof[e].
// Acsr stores are NON-TEMPORAL (written once, consumed next kernel): keeps
// the 200 MB write stream out of L2/L3 so PQ stays resident (round-4 FETCH
// was 212 MB vs ~60 MB expected -> write allocation was evicting PQ).
// ---------------------------------------------------------------------------
__global__ __launch_bounds__(256) void edge_kernel(
    const int* __restrict__ xnode, const int* __restrict__ xneis,
    const int* __restrict__ etype, const float* __restrict__ dg,
    const int* __restrict__ posof, const ushort* __restrict__ PQ,
    const float* __restrict__ Wxi, const float* __restrict__ bxi,
    ushort* __restrict__ Acsr)
{
    __shared__ float WetB[NET * 64];
    int tid = threadIdx.x;
    for (int i = tid; i < NET * 64; i += 256) {
        int et = i >> 6, n = i & 63;
        WetB[i] = Wxi[n * KXW + 128 + et] + bxi[n];
    }
    __syncthreads();

    size_t g = (size_t)blockIdx.x * 256 + tid;
    int e = (int)(g >> 4), l = (int)(g & 15);
    if (e >= E) return;
    int p = posof[e];
    if (p < 0) return;

    int src = xnode[e] - 1;
    int dst = xneis[e] - 1;
    int et  = etype[e] - 1;
    float sc = MUS / dg[e];

    uint2 pu = *(const uint2*)(PQ + (size_t)src * 128 + l * 4);
    uint2 qu = *(const uint2*)(PQ + (size_t)dst * 128 + 64 + l * 4);
    float4 wb = *(const float4*)(WetB + et * 64 + l * 4);

    float v0 = bflo(pu.x) + bflo(qu.x) + wb.x;
    float v1 = bfhi(pu.x) + bfhi(qu.x) + wb.y;
    float v2 = bflo(pu.y) + bflo(qu.y) + wb.z;
    float v3 = bfhi(pu.y) + bfhi(qu.y) + wb.w;

    uint2v o;
    o.x = ((uint)(ushort)f2bf(fast_tanh(v0) * sc))
        | ((uint)(ushort)f2bf(fast_tanh(v1) * sc) << 16);
    o.y = ((uint)(ushort)f2bf(fast_tanh(v2) * sc))
        | ((uint)(ushort)f2bf(fast_tanh(v3) * sc) << 16);
    __builtin_nontemporal_store(o, (uint2v*)(Acsr + (size_t)p * 64 + l * 4));
}

// ---------------------------------------------------------------------------
// One recurrence step, ONE WAVE PER NODE: lane = el*8 + s; 8 edges in flight,
// butterfly-reduce over el. 8x the memory-level parallelism of round 4.
// ---------------------------------------------------------------------------
__global__ __launch_bounds__(256) void step_kernel(
    const float* __restrict__ Hin, float* __restrict__ Hout,
    const ushort* __restrict__ A, const int* __restrict__ esrc,
    const int* __restrict__ rowptr, const float* __restrict__ Bsum)
{
    int v = blockIdx.x * 4 + (threadIdx.x >> 6);
    if (v >= V) return;
    int lane = threadIdx.x & 63;
    int el = lane >> 3, s = lane & 7;

    int p0 = rowptr[v], p1 = rowptr[v + 1];

    float acc = 0.0f;
    for (int p = p0 + el; p < p1; p += 8) {
        int src = esrc[p];
        const float4* H4 = (const float4*)(Hin + (size_t)src * 8);
        float4 h0 = H4[0], h1 = H4[1];
        uint4 av = *(const uint4*)(A + (size_t)p * 64 + s * 8);
        acc += bflo(av.x) * h0.x + bfhi(av.x) * h0.y
             + bflo(av.y) * h0.z + bfhi(av.y) * h0.w
             + bflo(av.z) * h1.x + bfhi(av.z) * h1.y
             + bflo(av.w) * h1.z + bfhi(av.w) * h1.w;
    }
    acc += __shfl_xor(acc, 8);
    acc += __shfl_xor(acc, 16);
    acc += __shfl_xor(acc, 32);
    if (el == 0)
        Hout[(size_t)v * 8 + s] = acc + Bsum[(size_t)v * 8 + s];
}

// ---------------------------------------------------------------------------
// Epilogue
// ---------------------------------------------------------------------------
__global__ __launch_bounds__(256) void logits_kernel(
    const float* __restrict__ H, const float* __restrict__ W1,
    const float* __restrict__ b1, float* __restrict__ logits)
{
    int v = blockIdx.x * 256 + threadIdx.x;
    if (v >= V) return;
    float4 w0 = ((const float4*)W1)[0], w1 = ((const float4*)W1)[1];
    const float4* H4 = (const float4*)(H + (size_t)v * 8);
    float4 h0 = H4[0], h1 = H4[1];
    logits[v] = b1[0]
              + h0.x * w0.x + h0.y * w0.y + h0.z * w0.z + h0.w * w0.w
              + h1.x * w1.x + h1.y * w1.y + h1.z * w1.z + h1.w * w1.w;
}

__global__ __launch_bounds__(256) void reduce_max_kernel(
    const float* __restrict__ logits, float* __restrict__ partial)
{
    float m = -INFINITY;
    for (int v = blockIdx.x * 256 + threadIdx.x; v < V; v += 256 * 256)
        m = fmaxf(m, logits[v]);
    #pragma unroll
    for (int o = 32; o > 0; o >>= 1) m = fmaxf(m, __shfl_down(m, o));
    __shared__ float sm[4];
    if ((threadIdx.x & 63) == 0) sm[threadIdx.x >> 6] = m;
    __syncthreads();
    if (threadIdx.x == 0)
        partial[blockIdx.x] = fmaxf(fmaxf(sm[0], sm[1]), fmaxf(sm[2], sm[3]));
}

__global__ __launch_bounds__(256) void final_max_kernel(
    const float* __restrict__ partial, float* __restrict__ M)
{
    float m = partial[threadIdx.x];
    #pragma unroll
    for (int o = 32; o > 0; o >>= 1) m = fmaxf(m, __shfl_down(m, o));
    __shared__ float sm[4];
    if ((threadIdx.x & 63) == 0) sm[threadIdx.x >> 6] = m;
    __syncthreads();
    if (threadIdx.x == 0) *M = fmaxf(fmaxf(sm[0], sm[1]), fmaxf(sm[2], sm[3]));
}

__global__ __launch_bounds__(256) void sum_kernel(
    const float* __restrict__ H, const float* __restrict__ logits,
    const float* __restrict__ Mp, float* __restrict__ accum)
{
    const float M = *Mp;
    float se = 0.0f;
    float sh[8] = {0, 0, 0, 0, 0, 0, 0, 0};
    for (int v = blockIdx.x * 256 + threadIdx.x; v < V; v += 256 * 256) {
        float w = __expf(logits[v] - M);
        se += w;
        const float4* H4 = (const float4*)(H + (size_t)v * 8);
        float4 h0 = H4[0], h1 = H4[1];
        sh[0] += w * h0.x; sh[1] += w * h0.y; sh[2] += w * h0.z; sh[3] += w * h0.w;
        sh[4] += w * h1.x; sh[5] += w * h1.y; sh[6] += w * h1.z; sh[7] += w * h1.w;
    }
    #pragma unroll
    for (int o = 32; o > 0; o >>= 1) {
        se += __shfl_down(se, o);
        #pragma unroll
        for (int i = 0; i < 8; ++i) sh[i] += __shfl_down(sh[i], o);
    }
    if ((threadIdx.x & 63) == 0) {
        atomicAdd(&accum[8], se);
        #pragma unroll
        for (int i = 0; i < 8; ++i) atomicAdd(&accum[i], sh[i]);
    }
}

__global__ void final_kernel(const float* __restrict__ accum, float* __restrict__ out)
{
    if (threadIdx.x < 8) out[threadIdx.x] = tanhf(accum[threadIdx.x] / accum[8]);
}

// ---------------------------------------------------------------------------
extern "C" void kernel_launch(void* const* d_in, const int* in_sizes, int n_in,
                              void* d_out, int out_size, void* d_ws, size_t ws_size,
                              hipStream_t stream)
{
    const float* feat  = (const float*)d_in[0];
    const int*   xnode = (const int*)d_in[1];
    const int*   xneis = (const int*)d_in[2];
    const int*   etype = (const int*)d_in[3];
    const float* dg    = (const float*)d_in[4];
    const float* Hinit = (const float*)d_in[5];
    const float* Wxi   = (const float*)d_in[6];
    const float* bxi   = (const float*)d_in[7];
    const float* Wrou  = (const float*)d_in[8];
    const float* brou  = (const float*)d_in[9];
    const float* W1    = (const float*)d_in[10];
    const float* b1    = (const float*)d_in[11];

    char* ws = (char*)d_ws;
    auto alloc = [&](size_t bytes) -> char* {
        char* p = ws; ws += (bytes + 255) & ~(size_t)255; return p;
    };
    // Budget: ~255.3 MB total (fits 256 MiB ws)
    ushort* Acsr    = (ushort*)alloc((size_t)E * 64 * 2);     // 204.8 MB
    ushort* PQ      = (ushort*)alloc((size_t)V * 128 * 2);    // 25.6 MB (bf16)
    float*  B0      = (float*)alloc((size_t)V * 8 * 4);       // 3.2 MB
    float*  B1      = (float*)alloc((size_t)V * 8 * 4);       // 3.2 MB
    float*  Bsum    = (float*)alloc((size_t)V * 8 * 4);       // 3.2 MB
    int*    posof   = (int*)alloc((size_t)E * 4);             // 6.4 MB
    int*    esrc    = (int*)alloc((size_t)E * 4);             // 6.4 MB
    int*    count   = (int*)alloc((size_t)2 * V * 4);         // 0.8 MB (count+cursor)
    int*    cursor  = count + V;
    int*    scanned = (int*)alloc((size_t)V * 4);
    int*    rowptr  = (int*)alloc((size_t)(V + 1) * 4);
    int*    blocksum= (int*)alloc(512 * 4);
    int*    tops    = (int*)alloc(512 * 4);
    float*  logits  = (float*)alloc((size_t)V * 4);
    float*  pmax    = (float*)alloc(256 * 4);
    float*  Mp      = (float*)alloc(16);
    float*  accum   = (float*)alloc(64);

    hipMemsetAsync(count, 0, (size_t)2 * V * 4, stream);
    hist_kernel<<<(E + 255) / 256, 256, 0, stream>>>(xneis, count);
    scan_block_kernel<<<NB, 256, 0, stream>>>(count, scanned, blocksum);
    scan_tops_kernel<<<1, 512, 0, stream>>>(blocksum, tops, rowptr);
    add_offsets_kernel<<<NB, 256, 0, stream>>>(scanned, tops, rowptr);
    scatter_kernel<<<(E + 255) / 256, 256, 0, stream>>>(xnode, xneis, rowptr, cursor, posof, esrc);
    pq_kernel<<<(V / 16 + 3) / 4, 256, 0, stream>>>(feat, Wxi, PQ);
    bsum_kernel<<<NB, 256, 0, stream>>>(feat, count, Wrou, brou, Bsum);
    edge_kernel<<<(int)(((size_t)E * 16 + 255) / 256), 256, 0, stream>>>(
        xnode, xneis, etype, dg, posof, PQ, Wxi, bxi, Acsr);

    const float* Hcur = Hinit;
    float* bufs[2] = {B0, B1};
    for (int t = 0; t < 4; ++t) {
        float* Hn = bufs[t & 1];
        step_kernel<<<(V + 3) / 4, 256, 0, stream>>>(Hcur, Hn, Acsr, esrc, rowptr, Bsum);
        Hcur = Hn;
    }

    logits_kernel<<<NB, 256, 0, stream>>>(Hcur, W1, b1, logits);
    reduce_max_kernel<<<256, 256, 0, stream>>>(logits, pmax);
    final_max_kernel<<<1, 256, 0, stream>>>(pmax, Mp);
    hipMemsetAsync(accum, 0, 64, stream);
    sum_kernel<<<256, 256, 0, stream>>>(Hcur, logits, Mp, accum);
    final_kernel<<<1, 64, 0, stream>>>(accum, (float*)d_out);
}